// Round 2
// baseline (629.243 us; speedup 1.0000x reference)
//
#include <hip/hip_runtime.h>
#include <math.h>

// ROUND 2 = CALIBRATION BUILD: streams the logits TWICE (all bin statistics
// exactly double; ece_final uses inv_n = 1/(2N) so outputs are unchanged).
// Purpose: kernel_time = dur_us(this) - dur_us(round1) resolves how much of
// the ~555 us is kernel vs fixed harness overhead (ws poison fill etc.).

#define N_BINS 15
#define C 50
#define ROWS_PER_TILE 64                   // rows per tile, one row per lane
#define TILE_FLOATS (ROWS_PER_TILE * C)    // 3200 floats = 12800 B
#define WAVES_PER_BLOCK 2
#define BLOCK (WAVES_PER_BLOCK * 64)       // 128
#define GRID 768                           // 3 blocks/CU (LDS-limited) * 256 CU
#define N_GWAVES (GRID * WAVES_PER_BLOCK)  // 1536 global waves
#define PASSES 2                           // calibration: read logits twice

// ws layout: uint cnt[15] | uint acc[15] | float conf[15]

__device__ __forceinline__ void load_lds16(const float* g, float* l) {
    // async global->LDS DMA, 16B/lane; LDS dest = wave-uniform base + lane*16
    __builtin_amdgcn_global_load_lds(
        (const __attribute__((address_space(1))) unsigned int*)g,
        (__attribute__((address_space(3))) unsigned int*)l, 16, 0, 0);
}

// stage one 64x50 tile (12800 B): 12 full-wave DMAs + 1 half-wave DMA
__device__ __forceinline__ void stage_tile(const float* __restrict__ src,
                                           float* __restrict__ dst, int lane) {
    #pragma unroll
    for (int j = 0; j < 12; ++j)
        load_lds16(src + (j * 64 + lane) * 4, dst + j * 256);
    if (lane < 32)
        load_lds16(src + (12 * 64 + lane) * 4, dst + 12 * 256);
}

__global__ __launch_bounds__(BLOCK) void ece_accum(
    const float* __restrict__ logits,
    const int*   __restrict__ labels,
    unsigned int* __restrict__ ws_cnt,
    unsigned int* __restrict__ ws_acc,
    float*        __restrict__ ws_conf,
    int n_rows)
{
    // [wave][buffer][tile] double-buffered: 2*2*12800 = 51200 B -> 3 blocks/CU
    __shared__ float tiles[WAVES_PER_BLOCK][2][TILE_FLOATS];
    __shared__ unsigned int s_cnt[N_BINS];
    __shared__ unsigned int s_acc[N_BINS];
    __shared__ float        s_conf[N_BINS];

    const int tid = threadIdx.x;
    if (tid < N_BINS) { s_cnt[tid] = 0u; s_acc[tid] = 0u; s_conf[tid] = 0.0f; }
    __syncthreads();

    const int wave = tid >> 6;
    const int lane = tid & 63;

    // per-lane bin accumulators, register-resident (all indexing compile-time).
    // ca: count in low 16 bits, correct-count in high 16 (<=44 rows/lane/bin).
    unsigned int ca[N_BINS];
    float        cs[N_BINS];
    #pragma unroll
    for (int b = 0; b < N_BINS; ++b) { ca[b] = 0u; cs[b] = 0.0f; }

    const int n_tiles = n_rows / ROWS_PER_TILE;   // 32768 here
    const int n_virt  = n_tiles * PASSES;         // 2x stream (calibration)
    int t      = blockIdx.x * WAVES_PER_BLOCK + wave;
    int parity = 0;
    int lbl    = 0;

    if (t < n_virt) {                             // prologue: stage first tile
        const int rt = (t >= n_tiles) ? t - n_tiles : t;
        stage_tile(logits + (size_t)rt * TILE_FLOATS, &tiles[wave][0][0], lane);
        lbl = labels[rt * ROWS_PER_TILE + lane];  // coalesced b32
    }

    while (t < n_virt) {
        const int nxt = t + N_GWAVES;
        int lbl_nxt = 0;
        if (nxt < n_virt) {
            const int rn = (nxt >= n_tiles) ? nxt - n_tiles : nxt;
            // WAR: ds_reads of the buffer we are about to overwrite (consumed
            // two iterations ago) must be drained before the DMA lands.
            asm volatile("s_waitcnt lgkmcnt(0)" ::: "memory");
            stage_tile(logits + (size_t)rn * TILE_FLOATS,
                       &tiles[wave][parity ^ 1][0], lane);
            lbl_nxt = labels[rn * ROWS_PER_TILE + lane];
            // counted wait: the newest 14 vmem ops (13 DMA + 1 label) are the
            // prefetch -- leave them in flight, current tile is complete.
            asm volatile("s_waitcnt vmcnt(14)" ::: "memory");
        } else {
            asm volatile("s_waitcnt vmcnt(0)" ::: "memory");  // epilogue drain
        }

        // row `lane` of current tile: contiguous 50 floats, 8B-aligned
        const float2* __restrict__ r2 =
            (const float2*)(&tiles[wave][parity][0] + lane * C);
        float vals[C];
        #pragma unroll
        for (int k = 0; k < C / 2; ++k) {
            float2 p = r2[k];
            vals[2 * k]     = p.x;
            vals[2 * k + 1] = p.y;
        }

        float vmax = vals[0];
        int   amax = 0;
        #pragma unroll
        for (int k = 1; k < C; ++k)
            if (vals[k] > vmax) { vmax = vals[k]; amax = k; }  // first max kept

        float sum = 0.0f;
        #pragma unroll
        for (int k = 0; k < C; ++k) sum += __expf(vals[k] - vmax);
        float conf = 1.0f / sum;                 // == max(softmax(row))

        int bin = (int)ceilf(conf * 15.0f) - 1;  // searchsorted(uppers, left)
        bin = bin < 0 ? 0 : (bin > N_BINS - 1 ? N_BINS - 1 : bin);

        // register bin update: no LDS atomics in the hot loop
        const unsigned int inc = (amax == lbl) ? 0x10001u : 1u;
        #pragma unroll
        for (int b = 0; b < N_BINS; ++b) {
            const bool h = (bin == b);
            ca[b] += h ? inc : 0u;
            cs[b] += h ? conf : 0.0f;
        }

        lbl = lbl_nxt;
        parity ^= 1;
        t = nxt;
    }

    // wave-level butterfly reduce; one shared atomic per bin per wave (cold)
    #pragma unroll
    for (int b = 0; b < N_BINS; ++b) {
        unsigned int c = ca[b];
        float        f = cs[b];
        #pragma unroll
        for (int off = 32; off > 0; off >>= 1) {
            c += (unsigned int)__shfl_xor((int)c, off, 64);
            f += __shfl_xor(f, off, 64);
        }
        if (lane == 0) {
            atomicAdd(&s_cnt[b], c & 0xFFFFu);
            atomicAdd(&s_acc[b], c >> 16);
            atomicAdd(&s_conf[b], f);
        }
    }

    // leftover rows (n_rows % 64) — scalar path, block 0 only (0 here).
    // Processed PASSES times so remainder rows scale like tile rows.
    const int rem_start = n_tiles * ROWS_PER_TILE;
    const int rem = n_rows - rem_start;
    if (blockIdx.x == 0 && tid < rem) {
        for (int pass = 0; pass < PASSES; ++pass) {
            const float* __restrict__ r = logits + (size_t)(rem_start + tid) * C;
            float vmax = r[0];
            int   amax = 0;
            for (int k = 1; k < C; ++k) {
                float v = r[k];
                if (v > vmax) { vmax = v; amax = k; }
            }
            float sum = 0.0f;
            for (int k = 0; k < C; ++k) sum += __expf(r[k] - vmax);
            float conf = 1.0f / sum;
            int bin = (int)ceilf(conf * 15.0f) - 1;
            bin = bin < 0 ? 0 : (bin > N_BINS - 1 ? N_BINS - 1 : bin);
            atomicAdd(&s_cnt[bin], 1u);
            if (amax == labels[rem_start + tid]) atomicAdd(&s_acc[bin], 1u);
            atomicAdd(&s_conf[bin], conf);
        }
    }

    __syncthreads();
    if (tid < N_BINS && s_cnt[tid] != 0u) {
        atomicAdd(&ws_cnt[tid],  s_cnt[tid]);
        atomicAdd(&ws_acc[tid],  s_acc[tid]);
        atomicAdd(&ws_conf[tid], s_conf[tid]);
    }
}

__global__ __launch_bounds__(64) void ece_final(
    const unsigned int* __restrict__ ws_cnt,
    const unsigned int* __restrict__ ws_acc,
    const float*        __restrict__ ws_conf,
    float* __restrict__ out, float inv_n)
{
    // inv_n = 1/(PASSES*N): counts are PASSES-fold, so prop is exact;
    // avg_acc/avg_conf are ratios of equally-scaled terms -> unchanged.
    int i = threadIdx.x;
    float v = 0.0f;
    if (i < N_BINS) {
        float cnt      = (float)ws_cnt[i];      // exact (< 2^24)
        float prop     = cnt * inv_n;
        float denom    = fmaxf(cnt, 1.0f);
        float avg_acc  = (float)ws_acc[i] / denom;
        float avg_conf = ws_conf[i] / denom;
        float gap      = avg_conf - avg_acc;
        bool  nonempty = cnt > 0.0f;
        out[1 + i]  = nonempty ? gap * prop : 0.0f;   // bin_over_confidence
        out[16 + i] = prop;                            // prop_in_bin
        v = nonempty ? fabsf(gap) * prop : 0.0f;
    }
    v += __shfl_down(v, 8, 64);
    v += __shfl_down(v, 4, 64);
    v += __shfl_down(v, 2, 64);
    v += __shfl_down(v, 1, 64);
    if (i == 0) out[0] = v;                            // ece
}

extern "C" void kernel_launch(void* const* d_in, const int* in_sizes, int n_in,
                              void* d_out, int out_size, void* d_ws, size_t ws_size,
                              hipStream_t stream)
{
    const float* logits = (const float*)d_in[0];
    const int*   labels = (const int*)d_in[1];
    const int n_rows = in_sizes[1];

    unsigned int* ws_cnt  = (unsigned int*)d_ws;
    unsigned int* ws_acc  = ws_cnt + N_BINS;
    float*        ws_conf = (float*)(ws_acc + N_BINS);

    hipMemsetAsync(d_ws, 0, 3 * N_BINS * sizeof(float), stream);

    ece_accum<<<GRID, BLOCK, 0, stream>>>(logits, labels, ws_cnt, ws_acc, ws_conf, n_rows);
    ece_final<<<1, 64, 0, stream>>>(ws_cnt, ws_acc, ws_conf, (float*)d_out,
                                    1.0f / ((float)PASSES * (float)n_rows));
}

// Round 3
// 550.037 us; speedup vs baseline: 1.1440x; 1.1440x over previous
//
#include <hip/hip_runtime.h>
#include <math.h>

// Reverted to the best harness-verified build (549.9 us).
// Calibration (round 2, 2x-stream build) established:
//   marginal cost per full 428 MB input pass = 69.9 us = 6.12 TB/s
//   = ~95-97% of achievable HBM BW (fill calib 6.5 TB/s, ubench 6.3 TB/s).
// The kernel is at the memory roofline; the remaining ~490 us of dur_us is
// fixed harness overhead (1.678 GB ws-poison fills at ~255 us, restores,
// launch overhead) not addressable from kernel_launch.

#define N_BINS 15
#define C 50
#define ROWS_PER_TILE 64                   // rows staged per wave-iteration
#define TILE_FLOATS (ROWS_PER_TILE * C)    // 3200 floats = 12800 B
#define WAVES_PER_BLOCK 4
#define BLOCK (WAVES_PER_BLOCK * 64)
#define GRID 768                           // 3 blocks/CU * 256 CU, fully resident

// ws layout: uint cnt[15] | uint acc[15] | float conf[15]

__device__ __forceinline__ void load_lds16(const float* g, float* l) {
    // async global->LDS DMA, 16B/lane; LDS dest = wave-uniform base + lane*16
    __builtin_amdgcn_global_load_lds(
        (const __attribute__((address_space(1))) unsigned int*)g,
        (__attribute__((address_space(3))) unsigned int*)l, 16, 0, 0);
}

__global__ __launch_bounds__(BLOCK) void ece_accum(
    const float* __restrict__ logits,
    const int*   __restrict__ labels,
    unsigned int* __restrict__ ws_cnt,
    unsigned int* __restrict__ ws_acc,
    float*        __restrict__ ws_conf,
    int n_rows)
{
    __shared__ float tiles[WAVES_PER_BLOCK * TILE_FLOATS];   // 51200 B, unpadded
    __shared__ unsigned int s_cnt[N_BINS];
    __shared__ unsigned int s_acc[N_BINS];
    __shared__ float        s_conf[N_BINS];

    const int tid = threadIdx.x;
    if (tid < N_BINS) { s_cnt[tid] = 0u; s_acc[tid] = 0u; s_conf[tid] = 0.0f; }
    __syncthreads();

    const int wave = tid >> 6;
    const int lane = tid & 63;
    float* __restrict__ wtile = &tiles[wave * TILE_FLOATS];

    const int n_tiles  = n_rows / ROWS_PER_TILE;          // 32768 (exact here)
    const int gwave    = blockIdx.x * WAVES_PER_BLOCK + wave;
    const int n_gwaves = GRID * WAVES_PER_BLOCK;          // 3072

    for (int t = gwave; t < n_tiles; t += n_gwaves) {
        const float* __restrict__ src = logits + (size_t)t * TILE_FLOATS;

        // drain prior ds_reads before the DMA overwrites this wave's tile (WAR)
        asm volatile("s_waitcnt lgkmcnt(0)" ::: "memory");

        // stage 12800 B = 800 float4: 12 full-wave DMAs + 1 half-wave DMA,
        // all fire-and-forget -> 13 KB in flight per wave
        #pragma unroll
        for (int j = 0; j < 12; ++j)
            load_lds16(src + (j * 64 + lane) * 4, wtile + j * 256);
        if (lane < 32)
            load_lds16(src + (12 * 64 + lane) * 4, wtile + 12 * 256);

        int label = labels[t * ROWS_PER_TILE + lane];     // coalesced b32

        asm volatile("s_waitcnt vmcnt(0)" ::: "memory");  // DMA + label complete

        // row `lane` of this tile, contiguous 50 floats (200 B, 8B-aligned)
        const float2* __restrict__ r2 = (const float2*)(wtile + lane * C);
        float vals[C];
        #pragma unroll
        for (int k = 0; k < C / 2; ++k) {
            float2 p = r2[k];
            vals[2 * k]     = p.x;
            vals[2 * k + 1] = p.y;
        }

        float vmax = vals[0];
        int   amax = 0;
        #pragma unroll
        for (int k = 1; k < C; ++k)
            if (vals[k] > vmax) { vmax = vals[k]; amax = k; }  // first max kept

        float sum = 0.0f;
        #pragma unroll
        for (int k = 0; k < C; ++k) sum += __expf(vals[k] - vmax);
        float conf = 1.0f / sum;                // == max(softmax(row))

        int bin = (int)ceilf(conf * 15.0f) - 1; // searchsorted(uppers, conf, left)
        bin = bin < 0 ? 0 : (bin > N_BINS - 1 ? N_BINS - 1 : bin);

        atomicAdd(&s_cnt[bin], 1u);
        if (amax == label) atomicAdd(&s_acc[bin], 1u);
        atomicAdd(&s_conf[bin], conf);
    }

    // leftover rows (n_rows % 64) — scalar path, block 0 only (0 for this shape)
    const int rem_start = n_tiles * ROWS_PER_TILE;
    const int rem = n_rows - rem_start;
    if (blockIdx.x == 0 && tid < rem) {
        const float* __restrict__ r = logits + (size_t)(rem_start + tid) * C;
        float vmax = r[0];
        int   amax = 0;
        for (int k = 1; k < C; ++k) {
            float v = r[k];
            if (v > vmax) { vmax = v; amax = k; }
        }
        float sum = 0.0f;
        for (int k = 0; k < C; ++k) sum += __expf(r[k] - vmax);
        float conf = 1.0f / sum;
        int bin = (int)ceilf(conf * 15.0f) - 1;
        bin = bin < 0 ? 0 : (bin > N_BINS - 1 ? N_BINS - 1 : bin);
        atomicAdd(&s_cnt[bin], 1u);
        if (amax == labels[rem_start + tid]) atomicAdd(&s_acc[bin], 1u);
        atomicAdd(&s_conf[bin], conf);
    }

    __syncthreads();
    if (tid < N_BINS && s_cnt[tid] != 0u) {
        atomicAdd(&ws_cnt[tid],  s_cnt[tid]);
        atomicAdd(&ws_acc[tid],  s_acc[tid]);
        atomicAdd(&ws_conf[tid], s_conf[tid]);
    }
}

__global__ __launch_bounds__(64) void ece_final(
    const unsigned int* __restrict__ ws_cnt,
    const unsigned int* __restrict__ ws_acc,
    const float*        __restrict__ ws_conf,
    float* __restrict__ out, float inv_n)
{
    int i = threadIdx.x;
    float v = 0.0f;
    if (i < N_BINS) {
        float cnt      = (float)ws_cnt[i];      // exact (< 2^24)
        float prop     = cnt * inv_n;
        float denom    = fmaxf(cnt, 1.0f);
        float avg_acc  = (float)ws_acc[i] / denom;
        float avg_conf = ws_conf[i] / denom;
        float gap      = avg_conf - avg_acc;
        bool  nonempty = cnt > 0.0f;
        out[1 + i]  = nonempty ? gap * prop : 0.0f;   // bin_over_confidence
        out[16 + i] = prop;                            // prop_in_bin
        v = nonempty ? fabsf(gap) * prop : 0.0f;
    }
    v += __shfl_down(v, 8, 64);
    v += __shfl_down(v, 4, 64);
    v += __shfl_down(v, 2, 64);
    v += __shfl_down(v, 1, 64);
    if (i == 0) out[0] = v;                            // ece
}

extern "C" void kernel_launch(void* const* d_in, const int* in_sizes, int n_in,
                              void* d_out, int out_size, void* d_ws, size_t ws_size,
                              hipStream_t stream)
{
    const float* logits = (const float*)d_in[0];
    const int*   labels = (const int*)d_in[1];
    const int n_rows = in_sizes[1];

    unsigned int* ws_cnt  = (unsigned int*)d_ws;
    unsigned int* ws_acc  = ws_cnt + N_BINS;
    float*        ws_conf = (float*)(ws_acc + N_BINS);

    hipMemsetAsync(d_ws, 0, 3 * N_BINS * sizeof(float), stream);

    ece_accum<<<GRID, BLOCK, 0, stream>>>(logits, labels, ws_cnt, ws_acc, ws_conf, n_rows);
    ece_final<<<1, 64, 0, stream>>>(ws_cnt, ws_acc, ws_conf, (float*)d_out,
                                    1.0f / (float)n_rows);
}